// Round 13
// baseline (413.669 us; speedup 1.0000x reference)
//
#include <hip/hip_runtime.h>

typedef __attribute__((ext_vector_type(8))) short short8;
typedef __attribute__((ext_vector_type(4))) float f32x4;

#define HH 256
#define WW 256

// plane stride (elements) for all chunk-planed activation tensors: [ch][B*H*W][32]
static constexpr size_t PS_IN = (size_t)4 * HH * WW * 32;  // 8,388,608 elem

__device__ inline unsigned int f2bf(float x) {
  unsigned int u = __float_as_uint(x);
  return (u + 0x7fffu + ((u >> 16) & 1u)) >> 16;   // RTNE truncation to bf16
}
__device__ inline unsigned int pack2(float a, float b) {
  return f2bf(a) | (f2bf(b) << 16);
}

// ---------------- transpose x (fp32 NCHW) -> xcl bf16 chunk-planes [2][B*HW][32] ----
__global__ __launch_bounds__(256) void xpose_k(const float* __restrict__ x,
                                               unsigned short* __restrict__ xcl) {
  const int t = threadIdx.x;
  const int ci = t & 63;
  const int wv = t >> 6;
  const int x0 = blockIdx.x * 64;
  const int y  = blockIdx.y;
  const int b  = blockIdx.z;
  const float* src = x + ((size_t)(b * 64 + ci) * HH + y) * WW + x0 + wv;
  unsigned short* dst = xcl + (size_t)(ci >> 5) * PS_IN +
                        ((size_t)((b * HH + y) * WW) + x0 + wv) * 32 + (ci & 31);
#pragma unroll
  for (int k = 0; k < 16; ++k)
    dst[(size_t)k * 4 * 32] = (unsigned short)f2bf(src[4 * k]);
}

// ---------------- weight norm -> chunk-planes [CINK/32][tap][co][32] bf16 ----------------
template <int COUT, int CINK>
__global__ __launch_bounds__(256) void wnorm_k(const float* __restrict__ v,
                                               const float* __restrict__ g,
                                               unsigned short* __restrict__ out) {
  constexpr int N = CINK * 9;
  constexpr size_t APS = (size_t)9 * COUT * 32;
  const int co = blockIdx.x, t = threadIdx.x;
  const float* vb = v + (size_t)co * N;
  float s = 0.f;
  for (int i = t; i < N; i += 256) { float a = vb[i]; s += a * a; }
  for (int off = 32; off > 0; off >>= 1) s += __shfl_xor(s, off, 64);
  __shared__ float red[4];
  if ((t & 63) == 0) red[t >> 6] = s;
  __syncthreads();
  const float tot = red[0] + red[1] + red[2] + red[3];
  const float sc = g[co] / sqrtf(tot);
  for (int i = t; i < N; i += 256) {
    int ci = i / 9, tap = i - 9 * (i / 9);
    out[(size_t)(ci >> 5) * APS + ((size_t)tap * COUT + co) * 32 + (ci & 31)] =
        (unsigned short)f2bf(vb[i] * sc);
  }
}

// ---------------- dyn bank norms ----------------
__global__ __launch_bounds__(256) void dynnorm_k(const float* __restrict__ dyn_v,
                                                 const float* __restrict__ dyn_g,
                                                 float* __restrict__ dscale) {
  const int k = blockIdx.x, t = threadIdx.x;
  const float* vb = dyn_v + (size_t)k * 36864;
  float s = 0.f;
  for (int i = t; i < 36864; i += 256) { float a = vb[i]; s += a * a; }
  for (int off = 32; off > 0; off >>= 1) s += __shfl_xor(s, off, 64);
  __shared__ float red[4];
  if ((t & 63) == 0) red[t >> 6] = s;
  __syncthreads();
  if (t == 0) dscale[k] = dyn_g[k] / sqrtf(red[0] + red[1] + red[2] + red[3]);
}

// ---------------- per-sample mixed dyn weights (chunk-planes) + bias; zero page ----------
__global__ __launch_bounds__(256) void mix_k(const float* __restrict__ scale,
                                             const float* __restrict__ att_w,
                                             const float* __restrict__ att_b,
                                             const float* __restrict__ dyn_v,
                                             const float* __restrict__ dyn_b,
                                             const float* __restrict__ dscale,
                                             unsigned short* __restrict__ wbt,
                                             float* __restrict__ bias_b,
                                             float* __restrict__ zp) {
  const int blk = blockIdx.x;
  const int b = blk >> 6, co = blk & 63;
  const int t = threadIdx.x;
  float att[4], wsc[4];
  const float sc = scale[b];
  float mx = -1e30f;
#pragma unroll
  for (int k = 0; k < 4; ++k) { att[k] = sc * att_w[k] + att_b[k]; mx = fmaxf(mx, att[k]); }
  float den = 0.f;
#pragma unroll
  for (int k = 0; k < 4; ++k) { att[k] = expf(att[k] - mx); den += att[k]; }
#pragma unroll
  for (int k = 0; k < 4; ++k) { att[k] /= den; wsc[k] = att[k] * dscale[k]; }
  for (int i = t; i < 576; i += 256) {
    int ci = i / 9, tap = i - 9 * (i / 9);
    float w = 0.f;
#pragma unroll
    for (int k = 0; k < 4; ++k)
      w += wsc[k] * dyn_v[(((size_t)k * 64 + co) * 64 + ci) * 9 + tap];
    // wbt: [b][ci>>5][tap][co][32]
    wbt[(size_t)b * 36864 + (size_t)(ci >> 5) * 18432 + ((size_t)tap * 64 + co) * 32 + (ci & 31)] =
        (unsigned short)f2bf(w);
  }
  if (t == 0) {
    float bb = 0.f;
#pragma unroll
    for (int k = 0; k < 4; ++k) bb += att[k] * dyn_b[k * 64 + co];
    bias_b[blk] = bb;
  }
  if (blk == 0) zp[t] = 0.f;  // 1 KB zero page
}

// ---------------- MFMA 3x3 conv v13: 3 blocks/CU (12 waves), counted-vmcnt schedule ----
// 256 thr / 4 waves; tile 64co x 8r x 32c; wave w = rows 2w..2w+1; acc[4m][4n]; chunk 32ci.
// LDS 49152 B: [0,24576) input halo 10x34x32ci (21760 real + pad);
//              [24576), [36864): two A panels [dy][g][co] 12288 B (ping-pong).
// Per chunk: dx0{stageA(dx1)->Pb, ireg loads, compute(Pa), vmcnt(6)},
//            dx1{stageA(dx2)->Pa, compute(Pb), vmcnt(0)},
//            dx2{stageA(dx0,ch+1)->Pb, compute(Pa)},
//            write{ds_write ireg->ibuf, vmcnt(0) lgkmcnt(0)}; panels swap per chunk.
// Registers dieted for 3 waves/SIMD (<=168 combined): Af read per-dy (peak Bv32+Af16),
// 32-bit ws-relative input offsets + ok bitmask. __launch_bounds__(256,3).
template <int CIN, int COUT, bool RELU, bool DYN>
__global__ __launch_bounds__(256, 3) void conv3x3_mfma(const unsigned short* __restrict__ in_cl,
                                                       const unsigned short* __restrict__ wt,
                                                       const float* __restrict__ bias,
                                                       unsigned short* __restrict__ out_cl,
                                                       float* __restrict__ y_out,
                                                       float* __restrict__ pblk,
                                                       const float* __restrict__ zp,
                                                       const char* __restrict__ wsb) {
  constexpr int CO_TILES = COUT / 64;
  constexpr int NCH = CIN / 32;
  constexpr int NSLOT = 1360;                    // 10*34 px * 4 g
  constexpr size_t APS = (size_t)9 * COUT * 32;  // A chunk-plane stride (elements)
  const int tid = threadIdx.x;
  const int lane = tid & 63;
  const int wv = tid >> 6;   // 0..3
  const int l15 = lane & 15;
  const int lg = lane >> 4;

  // ---- XCD-aware swizzle (bijective: gridDim.x % 8 == 0) ----
  const int wg = (blockIdx.x & 7) * (gridDim.x >> 3) + (blockIdx.x >> 3);
  int tdec = wg;
  const int cot = tdec % CO_TILES; tdec /= CO_TILES;
  const int bx = tdec & 7; tdec >>= 3;
  const int by = tdec & 31; tdec >>= 5;
  const int bz = tdec;

  const int x0 = bx * 32;
  const int y0 = by * 8;
  const int co0 = cot * 64;

  const unsigned short* inb = in_cl + (size_t)bz * HH * WW * 32;  // within plane 0
  const unsigned short* wt_base = wt + (DYN ? (size_t)bz * NCH * APS : (size_t)0);
  const float* biasb = bias + (DYN ? bz * 64 : 0);

  __shared__ __align__(16) char lds[49152];

  // ---- input staging: 32-bit offsets from ws base (inverse-swizzled), ok bitmask ----
  unsigned ioff[6];
  unsigned okm = 0;
#pragma unroll
  for (int k = 0; k < 6; ++k) {
    const int u = k * 256 + tid;
    const int pair = u >> 3;
    const int s = ((u & 7) * 16) ^ ((pair & 7) << 4);
    const int parity = s >> 6;
    const int g = (s >> 4) & 3;
    const int px = 2 * pair + parity;
    const int row = px / 34, col = px - 34 * row;
    const int gy = y0 - 1 + row, gx = x0 - 1 + col;
    const bool ok = (u < NSLOT) && ((unsigned)gy < (unsigned)HH) && ((unsigned)gx < (unsigned)WW);
    const unsigned short* p = ok ? (inb + ((size_t)(gy * WW + gx)) * 32 + g * 8)
                                 : (const unsigned short*)zp;
    ioff[k] = (unsigned)((const char*)p - wsb);
    okm |= (ok ? 1u : 0u) << k;
  }
  // ---- A staging per-thread source sub-offset (elements), 3 uniform rounds ----
  unsigned asrc[3];
#pragma unroll
  for (int r = 0; r < 3; ++r) {
    const int slot = r * 256 + tid;
    const int dy = slot >> 8, g = (slot >> 6) & 3, co = slot & 63;
    asrc[r] = (unsigned)((dy * 3 * COUT + co0 + co) * 32 + g * 8);
  }

  f32x4 acc[4][4];
#pragma unroll
  for (int m = 0; m < 4; ++m)
#pragma unroll
    for (int n = 0; n < 4; ++n) acc[m][n] = (f32x4){0.f, 0.f, 0.f, 0.f};

#define STAGE_A(d, c, pbase)                                                        \
  do {                                                                              \
    _Pragma("unroll") for (int r_ = 0; r_ < 3; ++r_)                                \
        __builtin_amdgcn_global_load_lds(                                           \
            (const void*)(wt_base + (size_t)(c) * APS + asrc[r_] + (d) * COUT * 32),\
            (void*)(lds + (pbase) + (r_ * 256 + wv * 64) * 16), 16, 0, 0);          \
  } while (0)

  // ---- compute one dx phase: Bv once, Af per-dy (low reg pressure) ----
  auto phase = [&](int abase, int dxv) {
    short8 Bv[2][4];
#pragma unroll
    for (int c2 = 0; c2 < 2; ++c2)
#pragma unroll
      for (int bi = 0; bi < 4; ++bi) {
        const int px_ = (2 * wv + bi) * 34 + 16 * c2 + l15 + dxv;
        const int by_ = (px_ >> 1) * 128 + ((lg * 16 + (px_ & 1) * 64) ^ (((px_ >> 1) & 7) << 4));
        Bv[c2][bi] = *(const short8*)(lds + by_);
      }
#pragma unroll
    for (int dy = 0; dy < 3; ++dy) {
      short8 Af[4];
#pragma unroll
      for (int m = 0; m < 4; ++m)
        Af[m] = *(const short8*)(lds + abase + (dy * 4 + lg) * 1024 + (16 * m + l15) * 16);
      __builtin_amdgcn_s_setprio(1);
#pragma unroll
      for (int c2 = 0; c2 < 2; ++c2)
#pragma unroll
        for (int bi = 0; bi < 4; ++bi) {
          if (dy < ((bi > 1) ? (bi - 1) : 0) || dy > ((bi < 2) ? bi : 2)) continue;
          const int n_ = 2 * (bi - dy) + c2;
#pragma unroll
          for (int m = 0; m < 4; ++m)
            acc[m][n_] = __builtin_amdgcn_mfma_f32_16x16x32_bf16(Af[m], Bv[c2][bi],
                                                                 acc[m][n_], 0, 0, 0);
        }
      __builtin_amdgcn_s_setprio(0);
    }
  };

  // ---- prologue: input(0) + A(dx0,0)->P0; full drain ----
#pragma unroll
  for (int k = 0; k < 6; ++k)
    __builtin_amdgcn_global_load_lds((const void*)(wsb + ioff[k]),
                                     (void*)(lds + (k * 256 + wv * 64) * 16), 16, 0, 0);
  STAGE_A(0, 0, 24576);
  asm volatile("s_waitcnt vmcnt(0)" ::: "memory");
  __builtin_amdgcn_s_barrier();

  int pa = 24576, pb = 36864;
#pragma unroll 1
  for (int ch = 0; ch < NCH - 1; ++ch) {
    // ---- dx0: reads Pa; stage A(dx1)->Pb; issue next-chunk input reg-loads ----
    STAGE_A(1, ch, pb);
    __builtin_amdgcn_sched_barrier(0);  // pin FIFO order: A-stages before ireg loads
    uint4 ireg[6];
#pragma unroll
    for (int k = 0; k < 6; ++k)
      ireg[k] = *(const uint4*)(wsb + ioff[k] +
                                (size_t)(ch + 1) * (((okm >> k) & 1) ? PS_IN * 2 : 0));
    phase(pa, 0);
    asm volatile("s_waitcnt vmcnt(6)" ::: "memory");
    __builtin_amdgcn_s_barrier();
    // ---- dx1: reads Pb; stage A(dx2)->Pa ----
    STAGE_A(2, ch, pa);
    phase(pb, 1);
    asm volatile("s_waitcnt vmcnt(0)" ::: "memory");
    __builtin_amdgcn_s_barrier();
    // ---- dx2: reads Pa; stage A(dx0,ch+1)->Pb ----
    STAGE_A(0, ch + 1, pb);
    phase(pa, 2);
    __builtin_amdgcn_s_barrier();
    // ---- write phase: land next chunk's input into ibuf ----
#pragma unroll
    for (int k = 0; k < 6; ++k)
      *(uint4*)(lds + (size_t)(k * 256 + tid) * 16) = ireg[k];
    asm volatile("s_waitcnt vmcnt(0) lgkmcnt(0)" ::: "memory");
    __builtin_amdgcn_s_barrier();
    const int tp = pa; pa = pb; pb = tp;  // next dx0 reads where A(dx0,ch+1) landed
  }
  {  // ---- tail chunk ----
    STAGE_A(1, NCH - 1, pb);
    phase(pa, 0);
    asm volatile("s_waitcnt vmcnt(0)" ::: "memory");
    __builtin_amdgcn_s_barrier();
    STAGE_A(2, NCH - 1, pa);
    phase(pb, 1);
    asm volatile("s_waitcnt vmcnt(0)" ::: "memory");
    __builtin_amdgcn_s_barrier();
    phase(pa, 2);
  }
#undef STAGE_A

  float scol[4][4];
  if (DYN) {
#pragma unroll
    for (int m = 0; m < 4; ++m)
#pragma unroll
      for (int f = 0; f < 4; ++f) scol[m][f] = 0.f;
  }

#pragma unroll
  for (int m = 0; m < 4; ++m) {
    const f32x4 bs = *(const f32x4*)(biasb + co0 + 16 * m + 4 * lg);
#pragma unroll
    for (int n = 0; n < 4; ++n) {
      f32x4 v = acc[m][n] + bs;
      if (RELU) {
        v.x = fmaxf(v.x, 0.f); v.y = fmaxf(v.y, 0.f);
        v.z = fmaxf(v.z, 0.f); v.w = fmaxf(v.w, 0.f);
      }
      const int yy = y0 + 2 * wv + (n >> 1);
      const int xx = x0 + 16 * (n & 1) + l15;
      if (!DYN) {
        uint2 pk;
        pk.x = pack2(v.x, v.y);
        pk.y = pack2(v.z, v.w);
        const int co = co0 + 16 * m + 4 * lg;
        // out: [co>>5][B*HW][32]
        *(uint2*)(out_cl + (size_t)(co >> 5) * PS_IN +
                  ((size_t)((bz * HH + yy) * WW + xx)) * 32 + (co & 31)) = pk;
      } else {
        const size_t base = ((size_t)(bz * 64 + 16 * m + 4 * lg) * HH + yy) * WW + xx;
        y_out[base]             = v.x;
        y_out[base + 1 * 65536] = v.y;
        y_out[base + 2 * 65536] = v.z;
        y_out[base + 3 * 65536] = v.w;
        scol[m][0] += v.x; scol[m][1] += v.y; scol[m][2] += v.z; scol[m][3] += v.w;
      }
    }
  }
  if (DYN) {
#pragma unroll
    for (int m = 0; m < 4; ++m)
#pragma unroll
      for (int f = 0; f < 4; ++f) {
        float r = scol[m][f];
        r += __shfl_xor(r, 1, 64);
        r += __shfl_xor(r, 2, 64);
        r += __shfl_xor(r, 4, 64);
        r += __shfl_xor(r, 8, 64);
        scol[m][f] = r;
      }
    __syncthreads();  // LDS dead; reuse as fp32 scratch
    float* red = (float*)lds;
    if (l15 == 0) {
#pragma unroll
      for (int m = 0; m < 4; ++m)
#pragma unroll
        for (int f = 0; f < 4; ++f)
          red[wv * 64 + 16 * m + 4 * lg + f] = scol[m][f];
    }
    __syncthreads();
    if (tid < 64) {
      const float s = red[tid] + red[64 + tid] + red[128 + tid] + red[192 + tid];
      pblk[((size_t)bz * 256 + by * 8 + bx) * 64 + tid] = s;
    }
  }
}

// ---------------- SE gate: 4 blocks (one per sample) ----------------
__global__ __launch_bounds__(256) void gate_k(const float* __restrict__ pblk,
                                              const float* __restrict__ se_w1,
                                              const float* __restrict__ se_w2,
                                              float* __restrict__ gate) {
  const int b = blockIdx.x;
  const int t = threadIdx.x;
  const int c = t & 63, part = t >> 6;
  __shared__ float ps[4][64];
  __shared__ float p_s[64], h_s[16];
  float s = 0.f;
  for (int blk = part; blk < 256; blk += 4)
    s += pblk[((size_t)b * 256 + blk) * 64 + c];
  ps[part][c] = s;
  __syncthreads();
  if (t < 64) p_s[t] = (ps[0][t] + ps[1][t] + ps[2][t] + ps[3][t]) * (1.f / 65536.f);
  __syncthreads();
  if (t < 16) {
    float h = 0.f;
    for (int cc = 0; cc < 64; ++cc) h += p_s[cc] * se_w1[t * 64 + cc];
    h_s[t] = fmaxf(h, 0.f);
  }
  __syncthreads();
  if (t < 64) {
    float a = 0.f;
    for (int j = 0; j < 16; ++j) a += h_s[j] * se_w2[t * 16 + j];
    gate[b * 64 + t] = 1.f / (1.f + expf(-a));
  }
}

// ---------------- final: out = x + y*gate (in-place on d_out) ----------------
__global__ __launch_bounds__(256) void final_k(const float* __restrict__ x,
                                               const float* __restrict__ gate,
                                               float* __restrict__ out) {
  const size_t i = ((size_t)blockIdx.x * 256 + threadIdx.x) * 4;
  f32x4 yv = *(f32x4*)(out + i);
  const f32x4 xv = *(const f32x4*)(x + i);
  const float g = gate[(int)(i >> 16)];
  yv = xv + yv * g;
  *(f32x4*)(out + i) = yv;
}

// ---------------- workspace layout (batched) ----------------
static constexpr size_t SZ_XCL = (size_t)4 * 256 * 256 * 64 * 2;   // 33.55 MB
static constexpr size_t SZ_W   = (size_t)9 * 256 * 64 * 2;         // 294912
static constexpr size_t SZ_PBLK = (size_t)4 * 256 * 64 * 4;        // 262144

static constexpr size_t B_XCL = 0;                                 // also r2 (aliased)
static constexpr size_t B_R   = B_XCL + SZ_XCL;
static constexpr size_t B_W1T = B_R + 4 * SZ_XCL;                  // 134.2 MB of r
static constexpr size_t B_W2T = B_W1T + SZ_W;
static constexpr size_t B_WBT = B_W2T + SZ_W;
static constexpr size_t B_DSC = B_WBT + SZ_W;
static constexpr size_t B_BB  = B_DSC + 256;
static constexpr size_t B_GT  = B_BB + 1024;
static constexpr size_t B_ZP  = B_GT + 1024;
static constexpr size_t B_PBLK = B_ZP + 1024;
static constexpr size_t WS_BIG = B_PBLK + SZ_PBLK;

extern "C" void kernel_launch(void* const* d_in, const int* in_sizes, int n_in,
                              void* d_out, int out_size, void* d_ws, size_t ws_size,
                              hipStream_t stream) {
  (void)in_sizes; (void)n_in; (void)out_size;
  if (ws_size < WS_BIG) return;  // ~169 MB scratch required (harness provides it)

  const float* x     = (const float*)d_in[0];
  const float* scale = (const float*)d_in[1];
  const float* v1    = (const float*)d_in[2];
  const float* g1    = (const float*)d_in[3];
  const float* b1    = (const float*)d_in[4];
  const float* v2    = (const float*)d_in[5];
  const float* g2    = (const float*)d_in[6];
  const float* b2    = (const float*)d_in[7];
  const float* dyn_v = (const float*)d_in[8];
  const float* dyn_g = (const float*)d_in[9];
  const float* dyn_b = (const float*)d_in[10];
  const float* att_w = (const float*)d_in[11];
  const float* att_b = (const float*)d_in[12];
  const float* se_w1 = (const float*)d_in[13];
  const float* se_w2 = (const float*)d_in[14];
  float* out = (float*)d_out;

  char* ws = (char*)d_ws;
  unsigned short* xcl  = (unsigned short*)(ws + B_XCL);
  unsigned short* rbuf = (unsigned short*)(ws + B_R);
  unsigned short* r2   = (unsigned short*)(ws + B_XCL);  // aliases dead xcl
  unsigned short* w1t  = (unsigned short*)(ws + B_W1T);
  unsigned short* w2t  = (unsigned short*)(ws + B_W2T);
  unsigned short* wbt  = (unsigned short*)(ws + B_WBT);
  float* dscale = (float*)(ws + B_DSC);
  float* bias_b = (float*)(ws + B_BB);
  float* gate   = (float*)(ws + B_GT);
  float* zp     = (float*)(ws + B_ZP);
  float* pblk   = (float*)(ws + B_PBLK);

  xpose_k<<<dim3(4, 256, 4), 256, 0, stream>>>(x, xcl);
  wnorm_k<256, 64><<<256, 256, 0, stream>>>(v1, g1, w1t);
  wnorm_k<64, 256><<<64, 256, 0, stream>>>(v2, g2, w2t);
  dynnorm_k<<<4, 256, 0, stream>>>(dyn_v, dyn_g, dscale);
  mix_k<<<256, 256, 0, stream>>>(scale, att_w, att_b, dyn_v, dyn_b, dscale, wbt, bias_b, zp);

  // 1-D grids, all divisible by 8 (bijective XCD swizzle); 256-thread blocks
  conv3x3_mfma<64, 256, true, false><<<4096, 256, 0, stream>>>(
      xcl, w1t, b1, rbuf, nullptr, nullptr, zp, ws);
  conv3x3_mfma<256, 64, false, false><<<1024, 256, 0, stream>>>(
      rbuf, w2t, b2, r2, nullptr, nullptr, zp, ws);
  conv3x3_mfma<64, 64, false, true><<<1024, 256, 0, stream>>>(
      r2, wbt, bias_b, nullptr, out, pblk, zp, ws);

  gate_k<<<4, 256, 0, stream>>>(pblk, se_w1, se_w2, gate);
  final_k<<<16384, 256, 0, stream>>>(x, gate, out);
}

// Round 14
// 327.071 us; speedup vs baseline: 1.2648x; 1.2648x over previous
//
#include <hip/hip_runtime.h>

typedef __attribute__((ext_vector_type(8))) short short8;
typedef __attribute__((ext_vector_type(4))) float f32x4;

#define HH 256
#define WW 256

// plane stride (elements) for all chunk-planed activation tensors: [ch][B*H*W][32]
static constexpr size_t PS_IN = (size_t)4 * HH * WW * 32;  // 8,388,608

__device__ inline unsigned int f2bf(float x) {
  unsigned int u = __float_as_uint(x);
  return (u + 0x7fffu + ((u >> 16) & 1u)) >> 16;   // RTNE truncation to bf16
}
__device__ inline unsigned int pack2(float a, float b) {
  return f2bf(a) | (f2bf(b) << 16);
}

// ---------------- transpose x (fp32 NCHW) -> xcl bf16 chunk-planes [2][B*HW][32] ----
__global__ __launch_bounds__(256) void xpose_k(const float* __restrict__ x,
                                               unsigned short* __restrict__ xcl) {
  const int t = threadIdx.x;
  const int ci = t & 63;
  const int wv = t >> 6;
  const int x0 = blockIdx.x * 64;
  const int y  = blockIdx.y;
  const int b  = blockIdx.z;
  const float* src = x + ((size_t)(b * 64 + ci) * HH + y) * WW + x0 + wv;
  unsigned short* dst = xcl + (size_t)(ci >> 5) * PS_IN +
                        ((size_t)((b * HH + y) * WW) + x0 + wv) * 32 + (ci & 31);
#pragma unroll
  for (int k = 0; k < 16; ++k)
    dst[(size_t)k * 4 * 32] = (unsigned short)f2bf(src[4 * k]);
}

// ---------------- weight norm -> chunk-planes [CINK/32][tap][co][32] bf16 ----------------
template <int COUT, int CINK>
__global__ __launch_bounds__(256) void wnorm_k(const float* __restrict__ v,
                                               const float* __restrict__ g,
                                               unsigned short* __restrict__ out) {
  constexpr int N = CINK * 9;
  constexpr size_t APS = (size_t)9 * COUT * 32;
  const int co = blockIdx.x, t = threadIdx.x;
  const float* vb = v + (size_t)co * N;
  float s = 0.f;
  for (int i = t; i < N; i += 256) { float a = vb[i]; s += a * a; }
  for (int off = 32; off > 0; off >>= 1) s += __shfl_xor(s, off, 64);
  __shared__ float red[4];
  if ((t & 63) == 0) red[t >> 6] = s;
  __syncthreads();
  const float tot = red[0] + red[1] + red[2] + red[3];
  const float sc = g[co] / sqrtf(tot);
  for (int i = t; i < N; i += 256) {
    int ci = i / 9, tap = i - 9 * (i / 9);
    out[(size_t)(ci >> 5) * APS + ((size_t)tap * COUT + co) * 32 + (ci & 31)] =
        (unsigned short)f2bf(vb[i] * sc);
  }
}

// ---------------- dyn bank norms ----------------
__global__ __launch_bounds__(256) void dynnorm_k(const float* __restrict__ dyn_v,
                                                 const float* __restrict__ dyn_g,
                                                 float* __restrict__ dscale) {
  const int k = blockIdx.x, t = threadIdx.x;
  const float* vb = dyn_v + (size_t)k * 36864;
  float s = 0.f;
  for (int i = t; i < 36864; i += 256) { float a = vb[i]; s += a * a; }
  for (int off = 32; off > 0; off >>= 1) s += __shfl_xor(s, off, 64);
  __shared__ float red[4];
  if ((t & 63) == 0) red[t >> 6] = s;
  __syncthreads();
  if (t == 0) dscale[k] = dyn_g[k] / sqrtf(red[0] + red[1] + red[2] + red[3]);
}

// ---------------- per-sample mixed dyn weights (chunk-planes) + bias; zero page ----------
__global__ __launch_bounds__(256) void mix_k(const float* __restrict__ scale,
                                             const float* __restrict__ att_w,
                                             const float* __restrict__ att_b,
                                             const float* __restrict__ dyn_v,
                                             const float* __restrict__ dyn_b,
                                             const float* __restrict__ dscale,
                                             unsigned short* __restrict__ wbt,
                                             float* __restrict__ bias_b,
                                             float* __restrict__ zp) {
  const int blk = blockIdx.x;
  const int b = blk >> 6, co = blk & 63;
  const int t = threadIdx.x;
  float att[4], wsc[4];
  const float sc = scale[b];
  float mx = -1e30f;
#pragma unroll
  for (int k = 0; k < 4; ++k) { att[k] = sc * att_w[k] + att_b[k]; mx = fmaxf(mx, att[k]); }
  float den = 0.f;
#pragma unroll
  for (int k = 0; k < 4; ++k) { att[k] = expf(att[k] - mx); den += att[k]; }
#pragma unroll
  for (int k = 0; k < 4; ++k) { att[k] /= den; wsc[k] = att[k] * dscale[k]; }
  for (int i = t; i < 576; i += 256) {
    int ci = i / 9, tap = i - 9 * (i / 9);
    float w = 0.f;
#pragma unroll
    for (int k = 0; k < 4; ++k)
      w += wsc[k] * dyn_v[(((size_t)k * 64 + co) * 64 + ci) * 9 + tap];
    // wbt: [b][ci>>5][tap][co][32]
    wbt[(size_t)b * 36864 + (size_t)(ci >> 5) * 18432 + ((size_t)tap * 64 + co) * 32 + (ci & 31)] =
        (unsigned short)f2bf(w);
  }
  if (t == 0) {
    float bb = 0.f;
#pragma unroll
    for (int k = 0; k < 4; ++k) bb += att[k] * dyn_b[k * 64 + co];
    bias_b[blk] = bb;
  }
  if (blk == 0) zp[t] = 0.f;  // 1 KB zero page
}

// ---------------- MFMA 3x3 conv v11: counted-vmcnt 3-phase pipeline, chunk-plane staging -
// 512 thr / 8 waves; tile 64co x 16r x 32c; wave w = rows 2w..2w+1; acc[4m][4n]; chunk 32ci.
// LDS 128 KiB: input halo 18x34x32ci dbuf 2x40960; A per-dx panel [dy][g][co] tri-buffer.
// Phase (ch,dx): {ds_reads -> issue stage (2A gload_lds; +5I at dx0) -> 48 MFMA ->
//   s_waitcnt vmcnt(N) -> s_barrier}.  Waits: prologue 2; main {7,7,2}; tail {2,0,0}.
// Global layouts are chunk-planed (dense staged streams): activations [ch][B*HW][32],
// A panels [ch][tap][co][32].
template <int CIN, int COUT, bool RELU, bool DYN>
__global__ __launch_bounds__(512, 2) void conv3x3_mfma(const unsigned short* __restrict__ in_cl,
                                                       const unsigned short* __restrict__ wt,
                                                       const float* __restrict__ bias,
                                                       unsigned short* __restrict__ out_cl,
                                                       float* __restrict__ y_out,
                                                       float* __restrict__ pblk,
                                                       const float* __restrict__ zp) {
  constexpr int CO_TILES = COUT / 64;
  constexpr int NCH = CIN / 32;
  constexpr int NSLOT = 2448;
  constexpr size_t APS = (size_t)9 * COUT * 32;  // A chunk-plane stride
  const int tid = threadIdx.x;
  const int lane = tid & 63;
  const int wv = tid >> 6;   // 0..7
  const int l15 = lane & 15;
  const int lg = lane >> 4;

  // ---- XCD-aware swizzle (bijective: gridDim.x % 8 == 0) ----
  const int wg = (blockIdx.x & 7) * (gridDim.x >> 3) + (blockIdx.x >> 3);
  int tdec = wg;
  const int cot = tdec % CO_TILES; tdec /= CO_TILES;
  const int bx = tdec & 7; tdec >>= 3;
  const int by = tdec & 15; tdec >>= 4;
  const int bz = tdec;

  const int x0 = bx * 32;
  const int y0 = by * 16;
  const int co0 = cot * 64;

  const unsigned short* inb = in_cl + (size_t)bz * HH * WW * 32;  // within plane 0
  const unsigned short* wtb = wt + (DYN ? (size_t)bz * NCH * APS : (size_t)0);
  const float* biasb = bias + (DYN ? bz * 64 : 0);
  const unsigned short* zp16 = (const unsigned short*)zp;

  __shared__ __align__(16) char lds[131072];  // [0,40960): I0  [40960,81920): I1
                                              // [81920 + dx*16384): A[dx]

  // ---- input staging sources (inverse-swizzled), chunk-plane 0; 5 uniform rounds ----
  const unsigned short* sptr[5];
  size_t istep[5];
#pragma unroll
  for (int k = 0; k < 5; ++k) {
    const int u = k * 512 + tid;
    const int pair = u >> 3;
    const int s = ((u & 7) * 16) ^ ((pair & 7) << 4);
    const int parity = s >> 6;
    const int g = (s >> 4) & 3;
    const int px = 2 * pair + parity;
    const int row = px / 34, col = px - 34 * row;
    const int gy = y0 - 1 + row, gx = x0 - 1 + col;
    const bool ok = (u < NSLOT) && ((unsigned)gy < (unsigned)HH) && ((unsigned)gx < (unsigned)WW);
    sptr[k] = ok ? (inb + ((size_t)(gy * WW + gx)) * 32 + g * 8) : zp16;
    istep[k] = ok ? PS_IN : 0;
  }
  // ---- A staging decode, 2 uniform rounds (slot = [dy][g][co], 768 real of 1024) ----
  int dyA[2], gA[2], coA[2];
  bool aval[2];
#pragma unroll
  for (int r = 0; r < 2; ++r) {
    const int slot = r * 512 + tid;
    dyA[r] = slot >> 8;
    gA[r] = (slot >> 6) & 3;
    coA[r] = slot & 63;
    aval[r] = (slot < 768);
  }

  f32x4 acc[4][4];
#pragma unroll
  for (int m = 0; m < 4; ++m)
#pragma unroll
    for (int n = 0; n < 4; ++n) acc[m][n] = (f32x4){0.f, 0.f, 0.f, 0.f};

#define STAGE_I(c, IBOFS)                                                          \
  do {                                                                             \
    _Pragma("unroll") for (int k_ = 0; k_ < 5; ++k_)                               \
        __builtin_amdgcn_global_load_lds(                                          \
            (const void*)(sptr[k_] + (size_t)(c) * istep[k_]),                     \
            (void*)(lds + (IBOFS) + (k_ * 512 + wv * 64) * 16), 16, 0, 0);         \
  } while (0)

#define STAGE_A(d, c, bidx)                                                        \
  do {                                                                             \
    _Pragma("unroll") for (int r_ = 0; r_ < 2; ++r_) {                             \
      const unsigned short* s_ =                                                   \
          aval[r_] ? wt_base + (size_t)(c) * APS +                                 \
                         ((size_t)((dyA[r_] * 3 + (d)) * COUT + co0 + coA[r_])) * 32 + \
                         gA[r_] * 8                                                \
                   : zp16;                                                         \
      __builtin_amdgcn_global_load_lds(                                            \
          (const void*)s_,                                                         \
          (void*)(lds + 81920 + (bidx) * 16384 + (r_ * 512 + wv * 64) * 16), 16, 0, 0); \
    }                                                                              \
  } while (0)

#define PHASE(DXV, IBOFS, WAITN, ...)                                              \
  do {                                                                             \
    short8 Af[3][4], Bv[2][4];                                                     \
    {                                                                              \
      const char* aB_ = lds + 81920 + (DXV) * 16384;                               \
      _Pragma("unroll") for (int dy = 0; dy < 3; ++dy)                             \
          _Pragma("unroll") for (int m = 0; m < 4; ++m)                            \
              Af[dy][m] = *(const short8*)(aB_ + (dy * 4 + lg) * 1024 +            \
                                           (16 * m + l15) * 16);                   \
      const char* iB_ = lds + (IBOFS);                                             \
      _Pragma("unroll") for (int c2 = 0; c2 < 2; ++c2)                             \
          _Pragma("unroll") for (int bi = 0; bi < 4; ++bi) {                       \
        const int px_ = (2 * wv + bi) * 34 + 16 * c2 + l15 + (DXV);                \
        const int by_ = (px_ >> 1) * 128 +                                         \
                        ((lg * 16 + (px_ & 1) * 64) ^ (((px_ >> 1) & 7) << 4));    \
        Bv[c2][bi] = *(const short8*)(iB_ + by_);                                  \
      }                                                                            \
    }                                                                              \
    __VA_ARGS__;                                                                   \
    __builtin_amdgcn_s_setprio(1);                                                 \
    _Pragma("unroll") for (int c2 = 0; c2 < 2; ++c2)                               \
        _Pragma("unroll") for (int bi = 0; bi < 4; ++bi)                           \
            _Pragma("unroll") for (int dy = 0; dy < 3; ++dy) {                     \
      if (dy < ((bi > 1) ? (bi - 1) : 0) || dy > ((bi < 2) ? bi : 2)) continue;    \
      const int n_ = 2 * (bi - dy) + c2;                                           \
      _Pragma("unroll") for (int m = 0; m < 4; ++m)                                \
          acc[m][n_] = __builtin_amdgcn_mfma_f32_16x16x32_bf16(Af[dy][m],          \
                                                               Bv[c2][bi],        \
                                                               acc[m][n_], 0, 0, 0); \
    }                                                                              \
    __builtin_amdgcn_s_setprio(0);                                                 \
    asm volatile("s_waitcnt vmcnt(" #WAITN ")" ::: "memory");                      \
    __builtin_amdgcn_s_barrier();                                                  \
  } while (0)

  const unsigned short* wt_base = wtb;

  // ---- prologue: I(0)->buf0, A(d0,0)->A0, A(d1,0)->A1 ----
  STAGE_I(0, 0);
  STAGE_A(0, 0, 0);
  STAGE_A(1, 0, 1);
  asm volatile("s_waitcnt vmcnt(2)" ::: "memory");
  __builtin_amdgcn_s_barrier();

#pragma unroll 1
  for (int ch = 0; ch < NCH - 1; ++ch) {
    const int ib = (ch & 1) * 40960;
    const int ibn = 40960 - ib;
    PHASE(0, ib, 7, STAGE_A(2, ch, 2); STAGE_I(ch + 1, ibn));
    PHASE(1, ib, 7, STAGE_A(0, ch + 1, 0));
    PHASE(2, ib, 2, STAGE_A(1, ch + 1, 1));
  }
  {  // tail chunk
    const int ib = ((NCH - 1) & 1) * 40960;
    PHASE(0, ib, 2, STAGE_A(2, NCH - 1, 2));
    PHASE(1, ib, 0, (void)0);
    PHASE(2, ib, 0, (void)0);
  }
#undef PHASE
#undef STAGE_A
#undef STAGE_I

  float scol[4][4];
  if (DYN) {
#pragma unroll
    for (int m = 0; m < 4; ++m)
#pragma unroll
      for (int f = 0; f < 4; ++f) scol[m][f] = 0.f;
  }

#pragma unroll
  for (int m = 0; m < 4; ++m) {
    const f32x4 bs = *(const f32x4*)(biasb + co0 + 16 * m + 4 * lg);
#pragma unroll
    for (int n = 0; n < 4; ++n) {
      f32x4 v = acc[m][n] + bs;
      if (RELU) {
        v.x = fmaxf(v.x, 0.f); v.y = fmaxf(v.y, 0.f);
        v.z = fmaxf(v.z, 0.f); v.w = fmaxf(v.w, 0.f);
      }
      const int yy = y0 + 2 * wv + (n >> 1);
      const int xx = x0 + 16 * (n & 1) + l15;
      if (!DYN) {
        uint2 pk;
        pk.x = pack2(v.x, v.y);
        pk.y = pack2(v.z, v.w);
        const int co = co0 + 16 * m + 4 * lg;
        // out: [co>>5][B*HW][32]
        *(uint2*)(out_cl + (size_t)(co >> 5) * PS_IN +
                  ((size_t)((bz * HH + yy) * WW + xx)) * 32 + (co & 31)) = pk;
      } else {
        const size_t base = ((size_t)(bz * 64 + 16 * m + 4 * lg) * HH + yy) * WW + xx;
        y_out[base]             = v.x;
        y_out[base + 1 * 65536] = v.y;
        y_out[base + 2 * 65536] = v.z;
        y_out[base + 3 * 65536] = v.w;
        scol[m][0] += v.x; scol[m][1] += v.y; scol[m][2] += v.z; scol[m][3] += v.w;
      }
    }
  }
  if (DYN) {
#pragma unroll
    for (int m = 0; m < 4; ++m)
#pragma unroll
      for (int f = 0; f < 4; ++f) {
        float r = scol[m][f];
        r += __shfl_xor(r, 1, 64);
        r += __shfl_xor(r, 2, 64);
        r += __shfl_xor(r, 4, 64);
        r += __shfl_xor(r, 8, 64);
        scol[m][f] = r;
      }
    __syncthreads();  // LDS dead; reuse as fp32 scratch
    float* red = (float*)lds;
    if (l15 == 0) {
#pragma unroll
      for (int m = 0; m < 4; ++m)
#pragma unroll
        for (int f = 0; f < 4; ++f)
          red[wv * 64 + 16 * m + 4 * lg + f] = scol[m][f];
    }
    __syncthreads();
    if (tid < 64) {
      float s = 0.f;
#pragma unroll
      for (int w = 0; w < 8; ++w) s += red[w * 64 + tid];
      pblk[((size_t)bz * 128 + by * 8 + bx) * 64 + tid] = s;
    }
  }
}

// ---------------- SE gate: 4 blocks (one per sample) ----------------
__global__ __launch_bounds__(256) void gate_k(const float* __restrict__ pblk,
                                              const float* __restrict__ se_w1,
                                              const float* __restrict__ se_w2,
                                              float* __restrict__ gate) {
  const int b = blockIdx.x;
  const int t = threadIdx.x;
  const int c = t & 63, part = t >> 6;
  __shared__ float ps[4][64];
  __shared__ float p_s[64], h_s[16];
  float s = 0.f;
  for (int blk = part; blk < 128; blk += 4)
    s += pblk[((size_t)b * 128 + blk) * 64 + c];
  ps[part][c] = s;
  __syncthreads();
  if (t < 64) p_s[t] = (ps[0][t] + ps[1][t] + ps[2][t] + ps[3][t]) * (1.f / 65536.f);
  __syncthreads();
  if (t < 16) {
    float h = 0.f;
    for (int cc = 0; cc < 64; ++cc) h += p_s[cc] * se_w1[t * 64 + cc];
    h_s[t] = fmaxf(h, 0.f);
  }
  __syncthreads();
  if (t < 64) {
    float a = 0.f;
    for (int j = 0; j < 16; ++j) a += h_s[j] * se_w2[t * 16 + j];
    gate[b * 64 + t] = 1.f / (1.f + expf(-a));
  }
}

// ---------------- final: out = x + y*gate (in-place on d_out) ----------------
__global__ __launch_bounds__(256) void final_k(const float* __restrict__ x,
                                               const float* __restrict__ gate,
                                               float* __restrict__ out) {
  const size_t i = ((size_t)blockIdx.x * 256 + threadIdx.x) * 4;
  f32x4 yv = *(f32x4*)(out + i);
  const f32x4 xv = *(const f32x4*)(x + i);
  const float g = gate[(int)(i >> 16)];
  yv = xv + yv * g;
  *(f32x4*)(out + i) = yv;
}

// ---------------- workspace layout (batched) ----------------
static constexpr size_t SZ_XCL = (size_t)4 * 256 * 256 * 64 * 2;   // 33.55 MB
static constexpr size_t SZ_W   = (size_t)9 * 256 * 64 * 2;         // 294912
static constexpr size_t SZ_PBLK = (size_t)4 * 128 * 64 * 4;        // 131072

static constexpr size_t B_XCL = 0;                                 // also r2 (aliased)
static constexpr size_t B_R   = B_XCL + SZ_XCL;
static constexpr size_t B_W1T = B_R + 4 * SZ_XCL;                  // 134.2 MB of r
static constexpr size_t B_W2T = B_W1T + SZ_W;
static constexpr size_t B_WBT = B_W2T + SZ_W;
static constexpr size_t B_DSC = B_WBT + SZ_W;
static constexpr size_t B_BB  = B_DSC + 256;
static constexpr size_t B_GT  = B_BB + 1024;
static constexpr size_t B_ZP  = B_GT + 1024;
static constexpr size_t B_PBLK = B_ZP + 1024;
static constexpr size_t WS_BIG = B_PBLK + SZ_PBLK;

extern "C" void kernel_launch(void* const* d_in, const int* in_sizes, int n_in,
                              void* d_out, int out_size, void* d_ws, size_t ws_size,
                              hipStream_t stream) {
  (void)in_sizes; (void)n_in; (void)out_size;
  if (ws_size < WS_BIG) return;  // ~169 MB scratch required (harness provides it)

  const float* x     = (const float*)d_in[0];
  const float* scale = (const float*)d_in[1];
  const float* v1    = (const float*)d_in[2];
  const float* g1    = (const float*)d_in[3];
  const float* b1    = (const float*)d_in[4];
  const float* v2    = (const float*)d_in[5];
  const float* g2    = (const float*)d_in[6];
  const float* b2    = (const float*)d_in[7];
  const float* dyn_v = (const float*)d_in[8];
  const float* dyn_g = (const float*)d_in[9];
  const float* dyn_b = (const float*)d_in[10];
  const float* att_w = (const float*)d_in[11];
  const float* att_b = (const float*)d_in[12];
  const float* se_w1 = (const float*)d_in[13];
  const float* se_w2 = (const float*)d_in[14];
  float* out = (float*)d_out;

  char* ws = (char*)d_ws;
  unsigned short* xcl  = (unsigned short*)(ws + B_XCL);
  unsigned short* rbuf = (unsigned short*)(ws + B_R);
  unsigned short* r2   = (unsigned short*)(ws + B_XCL);  // aliases dead xcl
  unsigned short* w1t  = (unsigned short*)(ws + B_W1T);
  unsigned short* w2t  = (unsigned short*)(ws + B_W2T);
  unsigned short* wbt  = (unsigned short*)(ws + B_WBT);
  float* dscale = (float*)(ws + B_DSC);
  float* bias_b = (float*)(ws + B_BB);
  float* gate   = (float*)(ws + B_GT);
  float* zp     = (float*)(ws + B_ZP);
  float* pblk   = (float*)(ws + B_PBLK);

  xpose_k<<<dim3(4, 256, 4), 256, 0, stream>>>(x, xcl);
  wnorm_k<256, 64><<<256, 256, 0, stream>>>(v1, g1, w1t);
  wnorm_k<64, 256><<<64, 256, 0, stream>>>(v2, g2, w2t);
  dynnorm_k<<<4, 256, 0, stream>>>(dyn_v, dyn_g, dscale);
  mix_k<<<256, 256, 0, stream>>>(scale, att_w, att_b, dyn_v, dyn_b, dscale, wbt, bias_b, zp);

  // 1-D grids, all divisible by 8 (bijective XCD swizzle); 512-thread blocks
  conv3x3_mfma<64, 256, true, false><<<2048, 512, 0, stream>>>(
      xcl, w1t, b1, rbuf, nullptr, nullptr, zp);
  conv3x3_mfma<256, 64, false, false><<<512, 512, 0, stream>>>(
      rbuf, w2t, b2, r2, nullptr, nullptr, zp);
  conv3x3_mfma<64, 64, false, true><<<512, 512, 0, stream>>>(
      r2, wbt, bias_b, nullptr, out, pblk, zp);

  gate_k<<<4, 256, 0, stream>>>(pblk, se_w1, se_w2, gate);
  final_k<<<16384, 256, 0, stream>>>(x, gate, out);
}

// Round 15
// 314.166 us; speedup vs baseline: 1.3167x; 1.0411x over previous
//
#include <hip/hip_runtime.h>

typedef __attribute__((ext_vector_type(8))) short short8;
typedef __attribute__((ext_vector_type(4))) float f32x4;

#define HH 256
#define WW 256

// plane stride (elements) for all chunk-planed activation tensors: [ch][B*H*W][32]
static constexpr size_t PS_IN = (size_t)4 * HH * WW * 32;  // 8,388,608

__device__ inline unsigned int f2bf(float x) {
  unsigned int u = __float_as_uint(x);
  return (u + 0x7fffu + ((u >> 16) & 1u)) >> 16;   // RTNE truncation to bf16
}
__device__ inline unsigned int pack2(float a, float b) {
  return f2bf(a) | (f2bf(b) << 16);
}

// ---------------- transpose x (fp32 NCHW) -> xcl bf16 chunk-planes [2][B*HW][32] ----
// Coalesced: reads 64 contiguous floats per wave (lanes across W), LDS transpose,
// dense 32B writes per thread.
__global__ __launch_bounds__(256) void xpose_k(const float* __restrict__ x,
                                               unsigned short* __restrict__ xcl) {
  __shared__ unsigned short t16[64][66];  // [c][x], +2 pad
  const int t = threadIdx.x;
  const int x0 = blockIdx.x * 64;
  const int y  = blockIdx.y;
  const int b  = blockIdx.z;
  const int lane = t & 63, grp = t >> 6;
#pragma unroll
  for (int it = 0; it < 16; ++it) {
    const int c = it * 4 + grp;
    t16[c][lane] =
        (unsigned short)f2bf(x[((size_t)(b * 64 + c) * HH + y) * WW + x0 + lane]);
  }
  __syncthreads();
  const int xx = t & 63, ch = (t >> 6) & 1, q = t >> 7;  // q = ci quarter (16)
  unsigned int w[8];
#pragma unroll
  for (int j = 0; j < 8; ++j)
    w[j] = (unsigned)t16[ch * 32 + q * 16 + 2 * j][xx] |
           ((unsigned)t16[ch * 32 + q * 16 + 2 * j + 1][xx] << 16);
  unsigned short* dst = xcl + (size_t)ch * PS_IN +
                        ((size_t)((b * HH + y) * WW) + x0 + xx) * 32 + q * 16;
  *(uint4*)dst = *(uint4*)&w[0];
  *(uint4*)(dst + 8) = *(uint4*)&w[4];
}

// ---------------- weight norm -> chunk-planes [CINK/32][tap][co][32] bf16 ----------------
template <int COUT, int CINK>
__global__ __launch_bounds__(256) void wnorm_k(const float* __restrict__ v,
                                               const float* __restrict__ g,
                                               unsigned short* __restrict__ out) {
  constexpr int N = CINK * 9;
  constexpr size_t APS = (size_t)9 * COUT * 32;
  const int co = blockIdx.x, t = threadIdx.x;
  const float* vb = v + (size_t)co * N;
  float s = 0.f;
  for (int i = t; i < N; i += 256) { float a = vb[i]; s += a * a; }
  for (int off = 32; off > 0; off >>= 1) s += __shfl_xor(s, off, 64);
  __shared__ float red[4];
  if ((t & 63) == 0) red[t >> 6] = s;
  __syncthreads();
  const float tot = red[0] + red[1] + red[2] + red[3];
  const float sc = g[co] / sqrtf(tot);
  for (int i = t; i < N; i += 256) {
    int ci = i / 9, tap = i - 9 * (i / 9);
    out[(size_t)(ci >> 5) * APS + ((size_t)tap * COUT + co) * 32 + (ci & 31)] =
        (unsigned short)f2bf(vb[i] * sc);
  }
}

// ---------------- dyn bank norms ----------------
__global__ __launch_bounds__(256) void dynnorm_k(const float* __restrict__ dyn_v,
                                                 const float* __restrict__ dyn_g,
                                                 float* __restrict__ dscale) {
  const int k = blockIdx.x, t = threadIdx.x;
  const float* vb = dyn_v + (size_t)k * 36864;
  float s = 0.f;
  for (int i = t; i < 36864; i += 256) { float a = vb[i]; s += a * a; }
  for (int off = 32; off > 0; off >>= 1) s += __shfl_xor(s, off, 64);
  __shared__ float red[4];
  if ((t & 63) == 0) red[t >> 6] = s;
  __syncthreads();
  if (t == 0) dscale[k] = dyn_g[k] / sqrtf(red[0] + red[1] + red[2] + red[3]);
}

// ---------------- per-sample mixed dyn weights (chunk-planes) + bias; zero page ----------
__global__ __launch_bounds__(256) void mix_k(const float* __restrict__ scale,
                                             const float* __restrict__ att_w,
                                             const float* __restrict__ att_b,
                                             const float* __restrict__ dyn_v,
                                             const float* __restrict__ dyn_b,
                                             const float* __restrict__ dscale,
                                             unsigned short* __restrict__ wbt,
                                             float* __restrict__ bias_b,
                                             float* __restrict__ zp) {
  const int blk = blockIdx.x;
  const int b = blk >> 6, co = blk & 63;
  const int t = threadIdx.x;
  float att[4], wsc[4];
  const float sc = scale[b];
  float mx = -1e30f;
#pragma unroll
  for (int k = 0; k < 4; ++k) { att[k] = sc * att_w[k] + att_b[k]; mx = fmaxf(mx, att[k]); }
  float den = 0.f;
#pragma unroll
  for (int k = 0; k < 4; ++k) { att[k] = expf(att[k] - mx); den += att[k]; }
#pragma unroll
  for (int k = 0; k < 4; ++k) { att[k] /= den; wsc[k] = att[k] * dscale[k]; }
  for (int i = t; i < 576; i += 256) {
    int ci = i / 9, tap = i - 9 * (i / 9);
    float w = 0.f;
#pragma unroll
    for (int k = 0; k < 4; ++k)
      w += wsc[k] * dyn_v[(((size_t)k * 64 + co) * 64 + ci) * 9 + tap];
    // wbt: [b][ci>>5][tap][co][32]
    wbt[(size_t)b * 36864 + (size_t)(ci >> 5) * 18432 + ((size_t)tap * 64 + co) * 32 + (ci & 31)] =
        (unsigned short)f2bf(w);
  }
  if (t == 0) {
    float bb = 0.f;
#pragma unroll
    for (int k = 0; k < 4; ++k) bb += att[k] * dyn_b[k * 64 + co];
    bias_b[blk] = bb;
  }
  if (blk == 0) zp[t] = 0.f;  // 1 KB zero page
}

// ---------------- MFMA 3x3 conv v11: counted-vmcnt 3-phase pipeline, chunk-plane staging -
// 512 thr / 8 waves; tile 64co x 16r x 32c; wave w = rows 2w..2w+1; acc[4m][4n]; chunk 32ci.
// LDS 128 KiB: input halo 18x34x32ci dbuf 2x40960; A per-dx panel [dy][g][co] tri-buffer.
// Phase (ch,dx): {ds_reads -> issue stage (2A gload_lds; +5I at dx0) -> 48 MFMA ->
//   s_waitcnt vmcnt(N) -> s_barrier}.  Waits: prologue 2; main {7,7,2}; tail {2,0,0}.
// Global layouts are chunk-planed (dense staged streams): activations [ch][B*HW][32],
// A panels [ch][tap][co][32].
template <int CIN, int COUT, bool RELU, bool DYN>
__global__ __launch_bounds__(512, 2) void conv3x3_mfma(const unsigned short* __restrict__ in_cl,
                                                       const unsigned short* __restrict__ wt,
                                                       const float* __restrict__ bias,
                                                       unsigned short* __restrict__ out_cl,
                                                       float* __restrict__ y_out,
                                                       float* __restrict__ pblk,
                                                       const float* __restrict__ zp) {
  constexpr int CO_TILES = COUT / 64;
  constexpr int NCH = CIN / 32;
  constexpr int NSLOT = 2448;
  constexpr size_t APS = (size_t)9 * COUT * 32;  // A chunk-plane stride
  const int tid = threadIdx.x;
  const int lane = tid & 63;
  const int wv = tid >> 6;   // 0..7
  const int l15 = lane & 15;
  const int lg = lane >> 4;

  // ---- XCD-aware swizzle (bijective: gridDim.x % 8 == 0) ----
  const int wg = (blockIdx.x & 7) * (gridDim.x >> 3) + (blockIdx.x >> 3);
  int tdec = wg;
  const int cot = tdec % CO_TILES; tdec /= CO_TILES;
  const int bx = tdec & 7; tdec >>= 3;
  const int by = tdec & 15; tdec >>= 4;
  const int bz = tdec;

  const int x0 = bx * 32;
  const int y0 = by * 16;
  const int co0 = cot * 64;

  const unsigned short* inb = in_cl + (size_t)bz * HH * WW * 32;  // within plane 0
  const unsigned short* wtb = wt + (DYN ? (size_t)bz * NCH * APS : (size_t)0);
  const float* biasb = bias + (DYN ? bz * 64 : 0);
  const unsigned short* zp16 = (const unsigned short*)zp;

  __shared__ __align__(16) char lds[131072];  // [0,40960): I0  [40960,81920): I1
                                              // [81920 + dx*16384): A[dx]

  // ---- input staging sources (inverse-swizzled), chunk-plane 0; 5 uniform rounds ----
  const unsigned short* sptr[5];
  size_t istep[5];
#pragma unroll
  for (int k = 0; k < 5; ++k) {
    const int u = k * 512 + tid;
    const int pair = u >> 3;
    const int s = ((u & 7) * 16) ^ ((pair & 7) << 4);
    const int parity = s >> 6;
    const int g = (s >> 4) & 3;
    const int px = 2 * pair + parity;
    const int row = px / 34, col = px - 34 * row;
    const int gy = y0 - 1 + row, gx = x0 - 1 + col;
    const bool ok = (u < NSLOT) && ((unsigned)gy < (unsigned)HH) && ((unsigned)gx < (unsigned)WW);
    sptr[k] = ok ? (inb + ((size_t)(gy * WW + gx)) * 32 + g * 8) : zp16;
    istep[k] = ok ? PS_IN : 0;
  }
  // ---- A staging decode, 2 uniform rounds (slot = [dy][g][co], 768 real of 1024) ----
  int dyA[2], gA[2], coA[2];
  bool aval[2];
#pragma unroll
  for (int r = 0; r < 2; ++r) {
    const int slot = r * 512 + tid;
    dyA[r] = slot >> 8;
    gA[r] = (slot >> 6) & 3;
    coA[r] = slot & 63;
    aval[r] = (slot < 768);
  }

  f32x4 acc[4][4];
#pragma unroll
  for (int m = 0; m < 4; ++m)
#pragma unroll
    for (int n = 0; n < 4; ++n) acc[m][n] = (f32x4){0.f, 0.f, 0.f, 0.f};

#define STAGE_I(c, IBOFS)                                                          \
  do {                                                                             \
    _Pragma("unroll") for (int k_ = 0; k_ < 5; ++k_)                               \
        __builtin_amdgcn_global_load_lds(                                          \
            (const void*)(sptr[k_] + (size_t)(c) * istep[k_]),                     \
            (void*)(lds + (IBOFS) + (k_ * 512 + wv * 64) * 16), 16, 0, 0);         \
  } while (0)

#define STAGE_A(d, c, bidx)                                                        \
  do {                                                                             \
    _Pragma("unroll") for (int r_ = 0; r_ < 2; ++r_) {                             \
      const unsigned short* s_ =                                                   \
          aval[r_] ? wt_base + (size_t)(c) * APS +                                 \
                         ((size_t)((dyA[r_] * 3 + (d)) * COUT + co0 + coA[r_])) * 32 + \
                         gA[r_] * 8                                                \
                   : zp16;                                                         \
      __builtin_amdgcn_global_load_lds(                                            \
          (const void*)s_,                                                         \
          (void*)(lds + 81920 + (bidx) * 16384 + (r_ * 512 + wv * 64) * 16), 16, 0, 0); \
    }                                                                              \
  } while (0)

#define PHASE(DXV, IBOFS, WAITN, ...)                                              \
  do {                                                                             \
    short8 Af[3][4], Bv[2][4];                                                     \
    {                                                                              \
      const char* aB_ = lds + 81920 + (DXV) * 16384;                               \
      _Pragma("unroll") for (int dy = 0; dy < 3; ++dy)                             \
          _Pragma("unroll") for (int m = 0; m < 4; ++m)                            \
              Af[dy][m] = *(const short8*)(aB_ + (dy * 4 + lg) * 1024 +            \
                                           (16 * m + l15) * 16);                   \
      const char* iB_ = lds + (IBOFS);                                             \
      _Pragma("unroll") for (int c2 = 0; c2 < 2; ++c2)                             \
          _Pragma("unroll") for (int bi = 0; bi < 4; ++bi) {                       \
        const int px_ = (2 * wv + bi) * 34 + 16 * c2 + l15 + (DXV);                \
        const int by_ = (px_ >> 1) * 128 +                                         \
                        ((lg * 16 + (px_ & 1) * 64) ^ (((px_ >> 1) & 7) << 4));    \
        Bv[c2][bi] = *(const short8*)(iB_ + by_);                                  \
      }                                                                            \
    }                                                                              \
    __VA_ARGS__;                                                                   \
    __builtin_amdgcn_s_setprio(1);                                                 \
    _Pragma("unroll") for (int c2 = 0; c2 < 2; ++c2)                               \
        _Pragma("unroll") for (int bi = 0; bi < 4; ++bi)                           \
            _Pragma("unroll") for (int dy = 0; dy < 3; ++dy) {                     \
      if (dy < ((bi > 1) ? (bi - 1) : 0) || dy > ((bi < 2) ? bi : 2)) continue;    \
      const int n_ = 2 * (bi - dy) + c2;                                           \
      _Pragma("unroll") for (int m = 0; m < 4; ++m)                                \
          acc[m][n_] = __builtin_amdgcn_mfma_f32_16x16x32_bf16(Af[dy][m],          \
                                                               Bv[c2][bi],        \
                                                               acc[m][n_], 0, 0, 0); \
    }                                                                              \
    __builtin_amdgcn_s_setprio(0);                                                 \
    asm volatile("s_waitcnt vmcnt(" #WAITN ")" ::: "memory");                      \
    __builtin_amdgcn_s_barrier();                                                  \
  } while (0)

  const unsigned short* wt_base = wtb;

  // ---- prologue: I(0)->buf0, A(d0,0)->A0, A(d1,0)->A1 ----
  STAGE_I(0, 0);
  STAGE_A(0, 0, 0);
  STAGE_A(1, 0, 1);
  asm volatile("s_waitcnt vmcnt(2)" ::: "memory");
  __builtin_amdgcn_s_barrier();

#pragma unroll 1
  for (int ch = 0; ch < NCH - 1; ++ch) {
    const int ib = (ch & 1) * 40960;
    const int ibn = 40960 - ib;
    PHASE(0, ib, 7, STAGE_A(2, ch, 2); STAGE_I(ch + 1, ibn));
    PHASE(1, ib, 7, STAGE_A(0, ch + 1, 0));
    PHASE(2, ib, 2, STAGE_A(1, ch + 1, 1));
  }
  {  // tail chunk
    const int ib = ((NCH - 1) & 1) * 40960;
    PHASE(0, ib, 2, STAGE_A(2, NCH - 1, 2));
    PHASE(1, ib, 0, (void)0);
    PHASE(2, ib, 0, (void)0);
  }
#undef PHASE
#undef STAGE_A
#undef STAGE_I

  float scol[4][4];
  if (DYN) {
#pragma unroll
    for (int m = 0; m < 4; ++m)
#pragma unroll
      for (int f = 0; f < 4; ++f) scol[m][f] = 0.f;
  }

#pragma unroll
  for (int m = 0; m < 4; ++m) {
    const f32x4 bs = *(const f32x4*)(biasb + co0 + 16 * m + 4 * lg);
#pragma unroll
    for (int n = 0; n < 4; ++n) {
      f32x4 v = acc[m][n] + bs;
      if (RELU) {
        v.x = fmaxf(v.x, 0.f); v.y = fmaxf(v.y, 0.f);
        v.z = fmaxf(v.z, 0.f); v.w = fmaxf(v.w, 0.f);
      }
      const int yy = y0 + 2 * wv + (n >> 1);
      const int xx = x0 + 16 * (n & 1) + l15;
      if (!DYN) {
        uint2 pk;
        pk.x = pack2(v.x, v.y);
        pk.y = pack2(v.z, v.w);
        const int co = co0 + 16 * m + 4 * lg;
        // out: [co>>5][B*HW][32]
        *(uint2*)(out_cl + (size_t)(co >> 5) * PS_IN +
                  ((size_t)((bz * HH + yy) * WW + xx)) * 32 + (co & 31)) = pk;
      } else {
        const size_t base = ((size_t)(bz * 64 + 16 * m + 4 * lg) * HH + yy) * WW + xx;
        y_out[base]             = v.x;
        y_out[base + 1 * 65536] = v.y;
        y_out[base + 2 * 65536] = v.z;
        y_out[base + 3 * 65536] = v.w;
        scol[m][0] += v.x; scol[m][1] += v.y; scol[m][2] += v.z; scol[m][3] += v.w;
      }
    }
  }
  if (DYN) {
#pragma unroll
    for (int m = 0; m < 4; ++m)
#pragma unroll
      for (int f = 0; f < 4; ++f) {
        float r = scol[m][f];
        r += __shfl_xor(r, 1, 64);
        r += __shfl_xor(r, 2, 64);
        r += __shfl_xor(r, 4, 64);
        r += __shfl_xor(r, 8, 64);
        scol[m][f] = r;
      }
    __syncthreads();  // LDS dead; reuse as fp32 scratch
    float* red = (float*)lds;
    if (l15 == 0) {
#pragma unroll
      for (int m = 0; m < 4; ++m)
#pragma unroll
        for (int f = 0; f < 4; ++f)
          red[wv * 64 + 16 * m + 4 * lg + f] = scol[m][f];
    }
    __syncthreads();
    if (tid < 64) {
      float s = 0.f;
#pragma unroll
      for (int w = 0; w < 8; ++w) s += red[w * 64 + tid];
      pblk[((size_t)bz * 128 + by * 8 + bx) * 64 + tid] = s;
    }
  }
}

// ---------------- SE gate: 4 blocks (one per sample) ----------------
__global__ __launch_bounds__(256) void gate_k(const float* __restrict__ pblk,
                                              const float* __restrict__ se_w1,
                                              const float* __restrict__ se_w2,
                                              float* __restrict__ gate) {
  const int b = blockIdx.x;
  const int t = threadIdx.x;
  const int c = t & 63, part = t >> 6;
  __shared__ float ps[4][64];
  __shared__ float p_s[64], h_s[16];
  float s = 0.f;
  for (int blk = part; blk < 128; blk += 4)
    s += pblk[((size_t)b * 128 + blk) * 64 + c];
  ps[part][c] = s;
  __syncthreads();
  if (t < 64) p_s[t] = (ps[0][t] + ps[1][t] + ps[2][t] + ps[3][t]) * (1.f / 65536.f);
  __syncthreads();
  if (t < 16) {
    float h = 0.f;
    for (int cc = 0; cc < 64; ++cc) h += p_s[cc] * se_w1[t * 64 + cc];
    h_s[t] = fmaxf(h, 0.f);
  }
  __syncthreads();
  if (t < 64) {
    float a = 0.f;
    for (int j = 0; j < 16; ++j) a += h_s[j] * se_w2[t * 16 + j];
    gate[b * 64 + t] = 1.f / (1.f + expf(-a));
  }
}

// ---------------- final: out = x + y*gate (in-place on d_out), grid-stride ----------------
__global__ __launch_bounds__(256) void final_k(const float* __restrict__ x,
                                               const float* __restrict__ gate,
                                               float* __restrict__ out) {
  const size_t total = (size_t)4 * 64 * HH * WW;        // 16,777,216 elems
  const size_t stride = (size_t)2048 * 256 * 4;
  for (size_t i = ((size_t)blockIdx.x * 256 + threadIdx.x) * 4; i < total; i += stride) {
    f32x4 yv = *(f32x4*)(out + i);
    const f32x4 xv = *(const f32x4*)(x + i);
    const float g = gate[(int)(i >> 16)];
    yv = xv + yv * g;
    *(f32x4*)(out + i) = yv;
  }
}

// ---------------- workspace layout (batched) ----------------
static constexpr size_t SZ_XCL = (size_t)4 * 256 * 256 * 64 * 2;   // 33.55 MB
static constexpr size_t SZ_W   = (size_t)9 * 256 * 64 * 2;         // 294912
static constexpr size_t SZ_PBLK = (size_t)4 * 128 * 64 * 4;        // 131072

static constexpr size_t B_XCL = 0;                                 // also r2 (aliased)
static constexpr size_t B_R   = B_XCL + SZ_XCL;
static constexpr size_t B_W1T = B_R + 4 * SZ_XCL;                  // 134.2 MB of r
static constexpr size_t B_W2T = B_W1T + SZ_W;
static constexpr size_t B_WBT = B_W2T + SZ_W;
static constexpr size_t B_DSC = B_WBT + SZ_W;
static constexpr size_t B_BB  = B_DSC + 256;
static constexpr size_t B_GT  = B_BB + 1024;
static constexpr size_t B_ZP  = B_GT + 1024;
static constexpr size_t B_PBLK = B_ZP + 1024;
static constexpr size_t WS_BIG = B_PBLK + SZ_PBLK;

extern "C" void kernel_launch(void* const* d_in, const int* in_sizes, int n_in,
                              void* d_out, int out_size, void* d_ws, size_t ws_size,
                              hipStream_t stream) {
  (void)in_sizes; (void)n_in; (void)out_size;
  if (ws_size < WS_BIG) return;  // ~169 MB scratch required (harness provides it)

  const float* x     = (const float*)d_in[0];
  const float* scale = (const float*)d_in[1];
  const float* v1    = (const float*)d_in[2];
  const float* g1    = (const float*)d_in[3];
  const float* b1    = (const float*)d_in[4];
  const float* v2    = (const float*)d_in[5];
  const float* g2    = (const float*)d_in[6];
  const float* b2    = (const float*)d_in[7];
  const float* dyn_v = (const float*)d_in[8];
  const float* dyn_g = (const float*)d_in[9];
  const float* dyn_b = (const float*)d_in[10];
  const float* att_w = (const float*)d_in[11];
  const float* att_b = (const float*)d_in[12];
  const float* se_w1 = (const float*)d_in[13];
  const float* se_w2 = (const float*)d_in[14];
  float* out = (float*)d_out;

  char* ws = (char*)d_ws;
  unsigned short* xcl  = (unsigned short*)(ws + B_XCL);
  unsigned short* rbuf = (unsigned short*)(ws + B_R);
  unsigned short* r2   = (unsigned short*)(ws + B_XCL);  // aliases dead xcl
  unsigned short* w1t  = (unsigned short*)(ws + B_W1T);
  unsigned short* w2t  = (unsigned short*)(ws + B_W2T);
  unsigned short* wbt  = (unsigned short*)(ws + B_WBT);
  float* dscale = (float*)(ws + B_DSC);
  float* bias_b = (float*)(ws + B_BB);
  float* gate   = (float*)(ws + B_GT);
  float* zp     = (float*)(ws + B_ZP);
  float* pblk   = (float*)(ws + B_PBLK);

  xpose_k<<<dim3(4, 256, 4), 256, 0, stream>>>(x, xcl);
  wnorm_k<256, 64><<<256, 256, 0, stream>>>(v1, g1, w1t);
  wnorm_k<64, 256><<<64, 256, 0, stream>>>(v2, g2, w2t);
  dynnorm_k<<<4, 256, 0, stream>>>(dyn_v, dyn_g, dscale);
  mix_k<<<256, 256, 0, stream>>>(scale, att_w, att_b, dyn_v, dyn_b, dscale, wbt, bias_b, zp);

  // 1-D grids, all divisible by 8 (bijective XCD swizzle); 512-thread blocks
  conv3x3_mfma<64, 256, true, false><<<2048, 512, 0, stream>>>(
      xcl, w1t, b1, rbuf, nullptr, nullptr, zp);
  conv3x3_mfma<256, 64, false, false><<<512, 512, 0, stream>>>(
      rbuf, w2t, b2, r2, nullptr, nullptr, zp);
  conv3x3_mfma<64, 64, false, true><<<512, 512, 0, stream>>>(
      r2, wbt, bias_b, nullptr, out, pblk, zp);

  gate_k<<<4, 256, 0, stream>>>(pblk, se_w1, se_w2, gate);
  final_k<<<2048, 256, 0, stream>>>(x, gate, out);
}